// Round 10
// baseline (949.138 us; speedup 1.0000x reference)
//
#include <hip/hip_runtime.h>

typedef unsigned short u16;
typedef unsigned int uint;

using f32x4 = __attribute__((ext_vector_type(4))) float;
using bf16x8 = __attribute__((ext_vector_type(8))) __bf16;
using u32x4 = __attribute__((ext_vector_type(4))) uint;

static __device__ __forceinline__ bf16x8 as_bf16x8(uint4 u) {
    union { uint4 a; bf16x8 b; } c; c.a = u; return c.b;
}
static __device__ __forceinline__ bf16x8 as_bf16x8v(u32x4 u) {
    union { u32x4 a; bf16x8 b; } c; c.a = u; return c.b;
}
static __device__ __forceinline__ float bf2f(u16 h) {
    union { uint u; float f; } c; c.u = ((uint)h) << 16; return c.f;
}
static __device__ __forceinline__ u16 f2bf(float f) {
    union { float f; uint u; } c; c.f = f;
    uint u = c.u;
    return (u16)((u + 0x7fffu + ((u >> 16) & 1u)) >> 16);
}
static __device__ __forceinline__ float fast_sigmoid(float x) {
    x = fminf(30.f, fmaxf(-30.f, x));
    return __builtin_amdgcn_rcpf(1.0f + __builtin_amdgcn_exp2f(x * -1.44269504f));
}
static __device__ __forceinline__ float fast_tanh(float x) {
    x = fminf(15.f, fmaxf(-15.f, x));
    return 1.0f - 2.0f * __builtin_amdgcn_rcpf(1.0f + __builtin_amdgcn_exp2f(x * 2.88539008f));
}

static __device__ __forceinline__ u32x4 load_b128_sc0(const u16* p) {
    u32x4 r;
    asm volatile("global_load_dwordx4 %0, %1, off sc0" : "=v"(r) : "v"(p) : "memory");
    return r;
}
static __device__ __forceinline__ void wait_vm0_fence_sched() {
    asm volatile("s_waitcnt vmcnt(0)" ::: "memory");
    __builtin_amdgcn_sched_barrier(0);   // rule #18
}

// constant-index helpers (rule #20)
static __device__ __forceinline__ float vext(f32x4 v, int i) {
    float r = v[0];
    r = (i == 1) ? v[1] : r;
    r = (i == 2) ? v[2] : r;
    r = (i == 3) ? v[3] : r;
    return r;
}
static __device__ __forceinline__ float sel4(float a0, float a1, float a2, float a3, int i) {
    float r = a0;
    r = (i == 1) ? a1 : r;
    r = (i == 2) ? a2 : r;
    r = (i == 3) ? a3 : r;
    return r;
}

static __device__ __forceinline__ int detect_fp32(const uint* w, int nwords) {
    int hits = 0;
    for (int i = 0; i < nwords; ++i) { uint e = (w[i] >> 7) & 0xffu; hits += (e >= 0x80u); }
    return hits > (nwords >> 3);
}
static __device__ __forceinline__ u16 load_bf(const void* p, int i, int fp32) {
    return fp32 ? f2bf(((const float*)p)[i]) : ((const u16*)p)[i];
}

// Fragment-ordered weight pack: wp[((w*KSTEPS + ks)*4 + nt)*512 + lane*8 + j]
__global__ void pack_w(const void* wf, const void* wi, const void* wc, const void* wo,
                       const void* bbf, const void* bbi, const void* bbc, const void* bbo,
                       u16* __restrict__ wp, u16* __restrict__ bp, int K, int KSTEPS) {
    __shared__ int sfp;
    if (threadIdx.x == 0) sfp = detect_fp32((const uint*)wf, 256);
    __syncthreads();
    const int fp32 = sfp;
    int w = blockIdx.x / KSTEPS, ks = blockIdx.x % KSTEPS;
    int nt = threadIdx.x >> 6, lane = threadIdx.x & 63;
    int c16 = lane & 15, q = lane >> 4;
    int n = w * 64 + nt * 16 + c16;
    int u = n >> 2, g = n & 3;
    const void* W = (g == 0) ? wf : (g == 1) ? wi : (g == 2) ? wc : wo;
    union { u16 v[8]; uint4 u4; } tmp;
#pragma unroll
    for (int j = 0; j < 8; ++j) {
        int k = ks * 32 + q * 8 + j;
        tmp.v[j] = (k < K) ? load_bf(W, k * 256 + u, fp32) : (u16)0;
    }
    *(uint4*)(wp + ((w * KSTEPS + ks) * 4 + nt) * 512 + lane * 8) = tmp.u4;
    if (ks == 0 && threadIdx.x < 64) {
        int n2 = w * 64 + threadIdx.x;
        int g2 = n2 & 3;
        const void* B = (g2 == 0) ? bbf : (g2 == 1) ? bbi : (g2 == 2) ? bbc : bbo;
        bp[n2] = load_bf(B, n2 >> 2, fp32);
    }
}

__global__ void pack_misc(const void* emb, const void* w_out, const void* b_out,
                          u16* __restrict__ embp, u16* __restrict__ wob,
                          u16* __restrict__ bob, uint* __restrict__ hzero) {
    __shared__ int sfp;
    if (threadIdx.x == 0) sfp = detect_fp32((const uint*)emb, 256);
    __syncthreads();
    const int fp32 = sfp;
    int gid = blockIdx.x * blockDim.x + threadIdx.x;
    int stride = gridDim.x * blockDim.x;
    for (int i = gid; i < 1000000; i += stride)
        embp[i] = load_bf(emb, i, fp32);
    // zero h1g+h2g (2MB = 524288 uints) + flags (4 groups-kinds x 8 x 64 = 2048)
    for (int i = gid; i < 526336; i += stride) hzero[i] = 0;
    if (blockIdx.x == 0) {
        __shared__ int sfp2;
        if (threadIdx.x == 0) sfp2 = detect_fp32((const uint*)w_out, 128);
        __syncthreads();
        if (threadIdx.x < 256) wob[threadIdx.x] = load_bf(w_out, threadIdx.x, sfp2);
        if (threadIdx.x == 0) bob[0] = load_bf(b_out, 0, sfp2);
    }
}

// Wait: poll 16 flags with sc0 (XCD-L2 hits); LLC-atomic safety net every 8th
// poll (cannot hang even if the block->XCD mapping assumption breaks).
static __device__ __forceinline__ void rg_wait(uint* grp, uint phase, int tid) {
    if (tid < 64) {
        const uint* fp = grp + (tid & 15);
        uint* cnt = grp + 32;
        int k = 0;
        while (true) {
            uint v;
            asm volatile("global_load_dword %0, %1, off sc0\n\t"
                         "s_waitcnt vmcnt(0)"
                         : "=v"(v) : "v"(fp) : "memory");
            if (__all((int)(v >= phase))) break;
            if (((++k) & 7) == 0 &&
                __hip_atomic_load(cnt, __ATOMIC_RELAXED,
                                  __HIP_MEMORY_SCOPE_AGENT) >= 16u * phase)
                break;
        }
    }
    __syncthreads();
}

// Coalesced publish: after a block sync covering the LDS stage writes, wave 0
// alone copies the 2KB stage -> global h-slab (2 x dwordx4 per lane, 32
// transactions vs ~1024 scattered u16), drains (vmcnt is per-WAVE), then
// stores the flag (sc0) + LLC safety counter. No second block-wide sync —
// waves 1..15 continue immediately.
#define PUBLISH(stg, dstbase, grp, phval)                                      \
    __syncthreads();                                                           \
    if (tid < 64) {                                                            \
        const uint4* s4 = (const uint4*)(stg);                                 \
        uint4 v0 = s4[lane * 2], v1 = s4[lane * 2 + 1];                        \
        u16* dp = (dstbase) + g * 1024 + lane * 16;                            \
        *(uint4*)dp = v0;                                                      \
        *(uint4*)(dp + 8) = v1;                                                \
        asm volatile("s_waitcnt vmcnt(0)" ::: "memory");                       \
        if (tid == 0) {                                                        \
            uint* slot = (grp) + g;                                            \
            uint pv = (phval);                                                 \
            asm volatile("global_store_dword %0, %1, off sc0"                  \
                         :: "v"(slot), "v"(pv) : "memory");                    \
            __hip_atomic_fetch_add((grp) + 32, 1u, __ATOMIC_RELAXED,           \
                                   __HIP_MEMORY_SCOPE_AGENT);                  \
        }                                                                      \
    }

// Persistent-weight LSTM; 2 phase-shifted 64-row chains/block; split f1/f2
// flags so h1 publishes mid-iteration (short critical path) and h2 rides a
// half-iteration of slack. Grid 128 = 8 chain-pairs (bid&7, XCD-affine) x 16
// unit-groups. h layout block-major: h[par][ch][r2][g][row][ul].
#define CSLAB 16384

__global__ void __launch_bounds__(1024, 1)
lstm_kernel(const int* __restrict__ tokens, const u16* __restrict__ embp,
            const u16* __restrict__ wp1, const u16* __restrict__ b1p,
            const u16* __restrict__ wp2, const u16* __restrict__ b2p,
            const u16* __restrict__ wob, const u16* __restrict__ bob,
            u16* __restrict__ h1g, u16* __restrict__ h2g,
            uint* __restrict__ flags, float* __restrict__ out) {
    __shared__ __align__(16) u16 w1s[12 * 4 * 512];   // 49152 B
    __shared__ __align__(16) u16 w2s[16 * 4 * 512];   // 65536 B
    __shared__ __align__(16) u16 stg1[1024];          // 2048 B h1 stage
    __shared__ __align__(16) u16 stg2[1024];          // 2048 B h2 stage
    __shared__ __align__(16) float outscr[1024];      // 4096 B epilogue
    // 122880 B -> 1 block/CU

    const int tid = threadIdx.x;
    const int bid = blockIdx.x;
    const int r2 = bid & 7;
    const int g = bid >> 3;
    const int lane = tid & 63;
    const int wv = tid >> 6;
    const int mt = wv >> 2, nt = wv & 3;
    const int c16 = lane & 15, q = lane >> 4;
    const int rrf = mt * 16 + c16;
    const int loff = (q >> 1) * 1024 + rrf * 16 + (q & 1) * 8;

    const int b = lane & 3;
    const int ulz = nt * 4 + ((lane & 15) >> 2);
    const int gunit = g * 16 + ulz;
    const int rloc = mt * 16 + q * 4 + b;
    const int hlin = rloc * 16 + ulz;                 // stage index 0..1023

    {
        const uint4* s1 = (const uint4*)(wp1 + g * (12 * 4 * 512));
        uint4* d1 = (uint4*)w1s;
        for (int i = tid; i < 3072; i += 1024) d1[i] = s1[i];
        const uint4* s2 = (const uint4*)(wp2 + g * (16 * 4 * 512));
        uint4* d2 = (uint4*)w2s;
        for (int i = tid; i < 4096; i += 1024) d2[i] = s2[i];
    }
    ushort4 bl1 = *(const ushort4*)(b1p + gunit * 4);
    ushort4 bl2 = *(const ushort4*)(b2p + gunit * 4);
    const float b1f = bf2f(bl1.x), b1i = bf2f(bl1.y), b1c = bf2f(bl1.z), b1o = bf2f(bl1.w);
    const float b2f = bf2f(bl2.x), b2i = bf2f(bl2.y), b2c = bf2f(bl2.z), b2o = bf2f(bl2.w);
    float c1s[2] = {0.f, 0.f}, c2s[2] = {0.f, 0.f};
    uint* f1g[2] = {flags + ((0 * 2 + 0) * 8 + r2) * 64, flags + ((0 * 2 + 1) * 8 + r2) * 64};
    uint* f2g[2] = {flags + ((1 * 2 + 0) * 8 + r2) * 64, flags + ((1 * 2 + 1) * 8 + r2) * 64};
    __syncthreads();

    const u16* bp1 = w1s + nt * 512 + lane * 8;
    const u16* bp2 = w2s + nt * 512 + lane * 8;

    ushort4 xlo[4], xhi[4];
#define LOAD_X(ch, t)                                                          \
    {                                                                          \
        int row = r2 * 128 + (ch) * 64 + rrf;                                  \
        int tok = tokens[row * 80 + (t)];                                      \
        const u16* xb = embp + tok * 100 + q * 8;                              \
        _Pragma("unroll")                                                      \
        for (int k2 = 0; k2 < 4; ++k2) {                                       \
            xlo[k2] = *(const ushort4*)(xb + k2 * 32);                         \
            xhi[k2] = *(const ushort4*)(xb + k2 * 32 + 4);                     \
        }                                                                      \
    }
#define XFRAG(k2) ({ union { ushort4 a[2]; bf16x8 v; } xu;                     \
                     xu.a[0] = xlo[k2]; xu.a[1] = xhi[k2]; xu.v; })

#define GATES(accv, B0, B1, B2, B3, cref, hout)                                \
    {                                                                          \
        float v0 = vext(accv, b);                                              \
        float v1 = __shfl_xor(vext(accv, b ^ 1), 1, 64);                       \
        float v2 = __shfl_xor(vext(accv, b ^ 2), 2, 64);                       \
        float v3 = __shfl_xor(vext(accv, b ^ 3), 3, 64);                       \
        float zf = sel4(v0, v1, v2, v3, b);                                    \
        float zi = sel4(v0, v1, v2, v3, b ^ 1);                                \
        float zc = sel4(v0, v1, v2, v3, b ^ 2);                                \
        float zo = sel4(v0, v1, v2, v3, b ^ 3);                                \
        float gf = fast_sigmoid(zf + B0);                                      \
        float gi = fast_sigmoid(zi + B1);                                      \
        float gc = fast_tanh(zc + B2);                                         \
        float go = fast_sigmoid(zo + B3);                                      \
        float cn = gf * cref + gi * gc;                                        \
        cref = cn;                                                             \
        hout = f2bf(go * fast_tanh(cn));                                       \
    }

    // ---- prologue: h1(0) per chain (x-only GEMM); alternate stage buffers ----
    {
        LOAD_X(0, 0);
        f32x4 acc = (f32x4){0.f, 0.f, 0.f, 0.f};
#pragma unroll
        for (int k2 = 0; k2 < 4; ++k2)
            acc = __builtin_amdgcn_mfma_f32_16x16x32_bf16(
                XFRAG(k2), as_bf16x8(*(const uint4*)(bp1 + (8 + k2) * 2048)), acc, 0, 0, 0);
        u16 h1o;
        GATES(acc, b1f, b1i, b1c, b1o, c1s[0], h1o);
        stg1[hlin] = h1o;
        PUBLISH(stg1, h1g + ((0 * 2 + 0) * 8 + r2) * CSLAB, f1g[0], 1u);
    }
    {
        LOAD_X(1, 0);
        f32x4 acc = (f32x4){0.f, 0.f, 0.f, 0.f};
#pragma unroll
        for (int k2 = 0; k2 < 4; ++k2)
            acc = __builtin_amdgcn_mfma_f32_16x16x32_bf16(
                XFRAG(k2), as_bf16x8(*(const uint4*)(bp1 + (8 + k2) * 2048)), acc, 0, 0, 0);
        u16 h1o;
        GATES(acc, b1f, b1i, b1c, b1o, c1s[1], h1o);
        stg2[hlin] = h1o;
        PUBLISH(stg2, h1g + ((0 * 2 + 1) * 8 + r2) * CSLAB, f1g[1], 1u);
    }

    // ---- main loop ----
#pragma unroll 1
    for (int i = 0; i < 79; ++i) {
        const int p_h2r = (i + 1) & 1, p_h1r = i & 1;
        const int p_h2w = i & 1, p_h1w = (i + 1) & 1;
#pragma unroll 1
        for (int ch = 0; ch < 2; ++ch) {
            // -- pre-wait work: x gather + x-partial of z1(i+1) --
            LOAD_X(ch, i + 1);
            f32x4 acc1 = (f32x4){0.f, 0.f, 0.f, 0.f};
#pragma unroll
            for (int k2 = 0; k2 < 4; ++k2)
                acc1 = __builtin_amdgcn_mfma_f32_16x16x32_bf16(
                    XFRAG(k2), as_bf16x8(*(const uint4*)(bp1 + (8 + k2) * 2048)), acc1, 0, 0, 0);

            // -- h2(i-1): slack-rich wait (published a full iteration ago) --
            if (i) rg_wait(f2g[ch], (uint)i, tid);
            const u16* h2b = h2g + ((p_h2r * 2 + ch) * 8 + r2) * CSLAB + loff;
            u32x4 ag2[8];
#pragma unroll
            for (int ks = 0; ks < 8; ++ks) ag2[ks] = load_b128_sc0(h2b + ks * 2048);
            wait_vm0_fence_sched();
            f32x4 acc2 = (f32x4){0.f, 0.f, 0.f, 0.f};
#pragma unroll
            for (int ks = 0; ks < 8; ++ks)
                acc2 = __builtin_amdgcn_mfma_f32_16x16x32_bf16(
                    as_bf16x8v(ag2[ks]), as_bf16x8(*(const uint4*)(bp2 + ks * 2048)), acc2, 0, 0, 0);

            // -- THE synchronization point: h1(i) --
            rg_wait(f1g[ch], (uint)(i + 1), tid);
            const u16* h1b = h1g + ((p_h1r * 2 + ch) * 8 + r2) * CSLAB + loff;
            u32x4 ag1[8];
#pragma unroll
            for (int ks = 0; ks < 8; ++ks) ag1[ks] = load_b128_sc0(h1b + ks * 2048);
            wait_vm0_fence_sched();

            // -- critical path: z1 h1-part -> gates1 -> publish h1(i+1) --
#pragma unroll
            for (int ks = 0; ks < 8; ++ks)
                acc1 = __builtin_amdgcn_mfma_f32_16x16x32_bf16(
                    as_bf16x8v(ag1[ks]), as_bf16x8(*(const uint4*)(bp1 + ks * 2048)), acc1, 0, 0, 0);
            u16 h1o;
            GATES(acc1, b1f, b1i, b1c, b1o, c1s[ch], h1o);
            stg1[hlin] = h1o;
            PUBLISH(stg1, h1g + ((p_h1w * 2 + ch) * 8 + r2) * CSLAB, f1g[ch], (uint)(i + 2));

            // -- off critical path: z2 h1-part -> gates2 -> publish h2(i) --
#pragma unroll
            for (int ks = 0; ks < 8; ++ks)
                acc2 = __builtin_amdgcn_mfma_f32_16x16x32_bf16(
                    as_bf16x8v(ag1[ks]), as_bf16x8(*(const uint4*)(bp2 + (8 + ks) * 2048)), acc2, 0, 0, 0);
            u16 h2o;
            GATES(acc2, b2f, b2i, b2c, b2o, c2s[ch], h2o);
            stg2[hlin] = h2o;
            PUBLISH(stg2, h2g + ((p_h2w * 2 + ch) * 8 + r2) * CSLAB, f2g[ch], (uint)(i + 1));
        }
    }

    // ---- epilogue: z2(79) per chain ----
#pragma unroll 1
    for (int ch = 0; ch < 2; ++ch) {
        rg_wait(f2g[ch], 79u, tid);               // h2(78) parity 0
        const u16* h2b = h2g + ((0 * 2 + ch) * 8 + r2) * CSLAB + loff;
        u32x4 ag2[8];
#pragma unroll
        for (int ks = 0; ks < 8; ++ks) ag2[ks] = load_b128_sc0(h2b + ks * 2048);
        wait_vm0_fence_sched();
        f32x4 acc2 = (f32x4){0.f, 0.f, 0.f, 0.f};
#pragma unroll
        for (int ks = 0; ks < 8; ++ks)
            acc2 = __builtin_amdgcn_mfma_f32_16x16x32_bf16(
                as_bf16x8v(ag2[ks]), as_bf16x8(*(const uint4*)(bp2 + ks * 2048)), acc2, 0, 0, 0);
        rg_wait(f1g[ch], 80u, tid);               // h1(79) parity 1
        const u16* h1b = h1g + ((1 * 2 + ch) * 8 + r2) * CSLAB + loff;
        u32x4 ag1[8];
#pragma unroll
        for (int ks = 0; ks < 8; ++ks) ag1[ks] = load_b128_sc0(h1b + ks * 2048);
        wait_vm0_fence_sched();
#pragma unroll
        for (int ks = 0; ks < 8; ++ks)
            acc2 = __builtin_amdgcn_mfma_f32_16x16x32_bf16(
                as_bf16x8v(ag1[ks]), as_bf16x8(*(const uint4*)(bp2 + (8 + ks) * 2048)), acc2, 0, 0, 0);
        u16 h2o;
        GATES(acc2, b2f, b2i, b2c, b2o, c2s[ch], h2o);
        stg2[hlin] = h2o;
        PUBLISH(stg2, h2g + ((1 * 2 + ch) * 8 + r2) * CSLAB, f2g[ch], 80u);
    }
    rg_wait(f2g[0], 80u, tid);
    rg_wait(f2g[1], 80u, tid);

    // ---- output: sigmoid(h2 @ w_out + b_out) by g==0 blocks ----
    if (g == 0) {
#pragma unroll 1
        for (int ch = 0; ch < 2; ++ch) {
            const u16* base = h2g + ((1 * 2 + ch) * 8 + r2) * CSLAB;
            int rr = tid >> 4, s = tid & 15;
            const u16* hp = base + s * 1024 + rr * 16;
            u32x4 hv0 = load_b128_sc0(hp);
            u32x4 hv1 = load_b128_sc0(hp + 8);
            wait_vm0_fence_sched();
            const u16* wq = wob + s * 16;
            union { u32x4 v[2]; u16 h[16]; } hu; hu.v[0] = hv0; hu.v[1] = hv1;
            float dot = 0.f;
#pragma unroll
            for (int k = 0; k < 16; ++k) dot += bf2f(hu.h[k]) * bf2f(wq[k]);
            __syncthreads();
            outscr[rr * 16 + s] = dot;
            __syncthreads();
            if (tid < 64) {
                float ssum = 0.f;
                for (int k = 0; k < 16; ++k) ssum += outscr[tid * 16 + k];
                out[r2 * 128 + ch * 64 + tid] = fast_sigmoid(ssum + bf2f(bob[0]));
            }
        }
    }
}

extern "C" void kernel_launch(void* const* d_in, const int* in_sizes, int n_in,
                              void* d_out, int out_size, void* d_ws, size_t ws_size,
                              hipStream_t stream) {
    const int* tokens = (const int*)d_in[0];
    const void* emb = d_in[1];
    const void* wf1 = d_in[2];  const void* bf1_ = d_in[3];
    const void* wi1 = d_in[4];  const void* bi1_ = d_in[5];
    const void* wc1 = d_in[6];  const void* bc1_ = d_in[7];
    const void* wo1 = d_in[8];  const void* bo1_ = d_in[9];
    const void* wf2 = d_in[10]; const void* bf2_ = d_in[11];
    const void* wi2 = d_in[12]; const void* bi2_ = d_in[13];
    const void* wc2 = d_in[14]; const void* bc2_ = d_in[15];
    const void* wo2 = d_in[16]; const void* bo2_ = d_in[17];
    const void* w_out = d_in[18];
    const void* b_out = d_in[19];

    u16* wp1 = (u16*)d_ws;                 // 393216
    u16* wp2 = wp1 + 16 * 12 * 4 * 512;    // 524288
    u16* b1p = wp2 + 16 * 16 * 4 * 512;    // 1024
    u16* b2p = b1p + 1024;                 // 1024
    u16* wob = b2p + 1024;                 // 256
    u16* bob = wob + 256;                  // 8 (pad)
    u16* embp = bob + 8;                   // 1,000,000 (16B-aligned)
    u16* h1g = embp + 1000000;             // 2par x 2ch x 8 x 16384 = 524288
    u16* h2g = h1g + 524288;               // same
    uint* flags = (uint*)(h2g + 524288);   // 4 kinds x 8 x 64 uints = 2048

    pack_w<<<dim3(16 * 12), dim3(256), 0, stream>>>(wf1, wi1, wc1, wo1, bf1_, bi1_, bc1_, bo1_,
                                                    wp1, b1p, 356, 12);
    pack_w<<<dim3(16 * 16), dim3(256), 0, stream>>>(wf2, wi2, wc2, wo2, bf2_, bi2_, bc2_, bo2_,
                                                    wp2, b2p, 512, 16);
    pack_misc<<<dim3(512), dim3(256), 0, stream>>>(emb, w_out, b_out, embp, wob, bob, (uint*)h1g);
    lstm_kernel<<<dim3(128), dim3(1024), 0, stream>>>(tokens, embp, wp1, b1p, wp2, b2p,
                                                      wob, bob, h1g, h2g, flags, (float*)d_out);
}